// Round 3
// baseline (302.188 us; speedup 1.0000x reference)
//
#include <hip/hip_runtime.h>
#include <cstdint>
#include <cstddef>

#define F_ALPHA 0.5f
#define THRESH  0.5f
#define EPS8    1e-8f
#define EPS7    1e-7f
#define MAXM    64
#define CCLS    21
#define GGRP    4      // GTs per bp block

// ---------------------------------------------------------------------------
// Kernel A: per-GT best prior (bp). One block owns GGRP GTs of one image.
// Threads stride P keeping per-GT running (iou,p) max in REGISTERS; the
// cross-lane reduction happens ONCE at the end (u64 key butterfly).
// Also emits per-GT areas (garea) for the loss kernel's scalar-load bt loop.
// grid = (ceil(M/GGRP), B), block = 256.
// ---------------------------------------------------------------------------
__global__ __launch_bounds__(256)
void bp_kernel(const float4* __restrict__ dbox,
               const float4* __restrict__ gt,
               unsigned* __restrict__ bp,
               float* __restrict__ garea,
               int P, int M)
{
    __shared__ unsigned long long wkey[GGRP][4];

    const int b  = blockIdx.y;
    const int m0 = blockIdx.x * GGRP;
    const int t  = threadIdx.x;
    const int w  = t >> 6, lane = t & 63;

    float4 gb[GGRP]; float ga[GGRP];
    #pragma unroll
    for (int g = 0; g < GGRP; g++) {
        int m = min(m0 + g, M - 1);           // pad entries discarded later
        float4 gg = gt[(size_t)b * M + m];
        gb[g] = gg;
        ga[g] = (gg.z - gg.x) * (gg.w - gg.y);
    }

    float    bestv[GGRP];
    unsigned bestp[GGRP];
    #pragma unroll
    for (int g = 0; g < GGRP; g++) { bestv[g] = 0.f; bestp[g] = 0u; }

    for (int p = t; p < P; p += 256) {
        float4 d = dbox[p];
        float darea = (d.z - d.x) * (d.w - d.y);
        #pragma unroll
        for (int g = 0; g < GGRP; g++) {
            float4 gg = gb[g];
            float lx = fmaxf(d.x, gg.x), ly = fmaxf(d.y, gg.y);
            float rx = fminf(d.z, gg.z), ry = fminf(d.w, gg.w);
            float iw = fmaxf(rx - lx, 0.f), ih = fmaxf(ry - ly, 0.f);
            float inter = iw * ih;
            // fast rcp: feeds compares only
            float iou = inter * __builtin_amdgcn_rcpf(darea + ga[g] - inter);
            // strict > : within-thread ties keep lowest p (p increases)
            if (iou > bestv[g]) { bestv[g] = iou; bestp[g] = (unsigned)p; }
        }
    }

    // one-time reduction: key = iou_bits<<32 | ~p  (max => max iou, min p)
    #pragma unroll
    for (int g = 0; g < GGRP; g++) {
        unsigned long long k =
            ((unsigned long long)__float_as_uint(bestv[g]) << 32)
            | (unsigned long long)(0xFFFFFFFFu - bestp[g]);
        #pragma unroll
        for (int o = 1; o < 64; o <<= 1) {
            unsigned long long k2 = __shfl_xor(k, o, 64);
            if (k2 > k) k = k2;
        }
        if (lane == 0) wkey[g][w] = k;
    }
    __syncthreads();
    if (t < GGRP) {
        unsigned long long k0 = wkey[t][0], k1 = wkey[t][1];
        unsigned long long k2 = wkey[t][2], k3 = wkey[t][3];
        unsigned long long ka = (k0 > k1) ? k0 : k1;
        unsigned long long kb = (k2 > k3) ? k2 : k3;
        unsigned long long k  = (ka > kb) ? ka : kb;
        int m = m0 + t;
        if (m < M) {
            bp[(size_t)b * M + m] = 0xFFFFFFFFu - (unsigned)(k & 0xFFFFFFFFull);
            float4 gg = gt[(size_t)b * M + m];
            garea[(size_t)b * M + m] = (gg.z - gg.x) * (gg.w - gg.y);
        }
        // all-zero row: key stays (0, ~0) -> p = 0, matching argmax fallback
    }
}

// ---------------------------------------------------------------------------
// Kernel B: fused bt (per-prior best GT via SCALAR-pipe GT loads) + inverted
// force-match (LDS atomicMax table) + focal loss (conf staged in LDS, read
// ONCE into registers) + GIoU on positives.
// LDS instr per anchor cut ~190 -> ~15: the kernel was LDS-pipe-bound.
// ---------------------------------------------------------------------------
__global__ __launch_bounds__(256, 6)
void loss_kernel(const float4* __restrict__ locp,
                 const float*  __restrict__ conf,
                 const float4* __restrict__ dbox,
                 const float4* __restrict__ gt,
                 const float*  __restrict__ garea,
                 const int*    __restrict__ gtl,
                 const unsigned* __restrict__ bp,
                 double* __restrict__ partS,
                 int*    __restrict__ partC,
                 int P, int M)
{
    __shared__ float    scf[256 * CCLS];   // 21504 B conf tile
    __shared__ float4   tb[MAXM];          // GT boxes (divergent idx gather only)
    __shared__ int      tl[MAXM];
    __shared__ int      ovr[256];          // force-match override: GT j or -1
    __shared__ double   sv[4];
    __shared__ int      sc[4];

    const int t = threadIdx.x;
    const int b = blockIdx.y;
    const int p0 = blockIdx.x * 256;
    const int p = p0 + t;
    const bool valid = (p < P);

    ovr[t] = -1;
    if (t < M) {
        tb[t] = gt[(size_t)b * M + t];
        tl[t] = gtl[(size_t)b * M + t];
    }

    // stage conf tile: contiguous [cnt*21] floats, coalesced float4
    const int cnt = min(256, P - p0);
    const int nf = cnt * CCLS;
    const float* src = conf + ((size_t)b * P + p0) * CCLS;
    {
        const int n4 = nf >> 2;
        const float4* s4 = (const float4*)src;
        float4* d4 = (float4*)scf;
        for (int i = t; i < n4; i += 256) d4[i] = s4[i];
        for (int i = (n4 << 2) + t; i < nf; i += 256) scf[i] = src[i];
    }
    __syncthreads();

    // inverted force-match: last-wins == max GT index wins
    if (t < M) {
        unsigned q = bp[(size_t)b * M + t] - (unsigned)p0;
        if (q < 256u) atomicMax(&ovr[q], t);
    }

    // bt: best GT per prior. GT data arrives via wave-uniform (scalar) loads;
    // zero LDS traffic in this loop. Cross-mult compare (no rcp chain):
    // iou_m > iou_best  <=>  inter_m*bd > bi*den_m   (dens always > 0)
    float4 d = make_float4(0.f, 0.f, 0.f, 0.f);
    float bi = -1.0f, bd = 1.0f;   // first compare always true at m=0
    int   bm = 0;
    if (valid) {
        d = dbox[p];
        const float darea = (d.z - d.x) * (d.w - d.y);
        const float4* gtb = gt + (size_t)b * M;
        const float*  gab = garea + (size_t)b * M;
        const int Mpad = (M + 3) & ~3;
        for (int m0 = 0; m0 < Mpad; m0 += 4) {
            #pragma unroll
            for (int k = 0; k < 4; k++) {
                int mc = min(m0 + k, M - 1);   // pad = dup of last box: can
                float4 g = gtb[mc];            // never strictly win
                float ta = gab[mc];
                float lx = fmaxf(d.x, g.x), ly = fmaxf(d.y, g.y);
                float rx = fminf(d.z, g.z), ry = fminf(d.w, g.w);
                float iw = fmaxf(rx - lx, 0.f), ih = fmaxf(ry - ly, 0.f);
                float inter = iw * ih;
                float den = darea + ta - inter;
                if (inter * bd > bi * den) { bi = inter; bd = den; bm = m0 + k; }
            }
        }
    }
    __syncthreads();   // ovr table complete

    double acc = 0.0;
    int cnt_pos = 0;
    if (valid) {
        int  idx = bm;
        bool pos = (bi >= THRESH * bd);        // iou >= 0.5
        int j = ovr[t];
        if (j >= 0) { idx = j; pos = true; }
        int lbl = pos ? tl[idx] : 0;

        // focal loss: scf -> registers ONCE (static indexing only)
        float xv[CCLS];
        const float* x = scf + t * CCLS;
        #pragma unroll
        for (int c = 0; c < CCLS; c++) xv[c] = x[c];
        float xl = scf[t * CCLS + lbl];        // runtime index: straight to LDS
        float mx = xv[0];
        #pragma unroll
        for (int c = 1; c < CCLS; c++) mx = fmaxf(mx, xv[c]);
        float sum = 0.f;
        #pragma unroll
        for (int c = 0; c < CCLS; c++) sum += expf(xv[c] - mx);
        float ce = (mx + logf(sum)) - xl;
        float pt = expf(-ce);
        float om = 1.f - pt;
        acc = (double)(F_ALPHA * om * sqrtf(om) * ce);

        if (pos) {
            cnt_pos = 1;
            float dw = d.z - d.x, dh = d.w - d.y;
            float dcx = d.x + dw * 0.5f, dcy = d.y + dh * 0.5f;
            float4 g = tb[idx];
            float gw = g.z - g.x, gh = g.w - g.y;
            float gcx = g.x + gw * 0.5f, gcy = g.y + gh * 0.5f;
            float ex = (gcx - dcx) / (dw + EPS8);
            float ey = (gcy - dcy) / (dh + EPS8);
            float ew = logf(gw / (dw + EPS8) + EPS8);
            float eh = logf(gh / (dh + EPS8) + EPS8);
            float tcx = ex * dw + dcx, tcy = ey * dh + dcy;
            float tw = expf(ew) * dw,  th = expf(eh) * dh;
            float t0 = tcx - tw * 0.5f, t1 = tcy - th * 0.5f;
            float t2 = tcx + tw * 0.5f, t3 = tcy + th * 0.5f;
            float4 l = locp[(size_t)b * P + p];
            float pcx = l.x * dw + dcx, pcy = l.y * dh + dcy;
            float pw = expf(l.z) * dw,  ph = expf(l.w) * dh;
            float q0 = pcx - pw * 0.5f, q1 = pcy - ph * 0.5f;
            float q2 = pcx + pw * 0.5f, q3 = pcy + ph * 0.5f;
            float ix0 = fmaxf(q0, t0), iy0 = fmaxf(q1, t1);
            float ix1 = fminf(q2, t2), iy1 = fminf(q3, t3);
            float iw = fmaxf(ix1 - ix0, 0.f), ih = fmaxf(iy1 - iy0, 0.f);
            float inter = iw * ih;
            float pa = (q2 - q0) * (q3 - q1);
            float ta = (t2 - t0) * (t3 - t1);
            float uni = pa + ta - inter;
            float iou = inter / (uni + EPS7);
            float e0 = fminf(q0, t0), e1 = fminf(q1, t1);
            float e2 = fmaxf(q2, t2), e3 = fmaxf(q3, t3);
            float ewd = fmaxf(e2 - e0, 0.f), ehd = fmaxf(e3 - e1, 0.f);
            float encl = ewd * ehd;
            float giou = iou - (encl - uni) / (encl + EPS7);
            acc += (double)(1.f - giou);
        }
    }

    for (int o = 32; o > 0; o >>= 1) {
        acc += __shfl_down(acc, o, 64);
        cnt_pos += __shfl_down(cnt_pos, o, 64);
    }
    int w = t >> 6, lane = t & 63;
    if (lane == 0) { sv[w] = acc; sc[w] = cnt_pos; }
    __syncthreads();
    if (t == 0) {
        int slot = blockIdx.y * gridDim.x + blockIdx.x;
        partS[slot] = sv[0] + sv[1] + sv[2] + sv[3];
        partC[slot] = sc[0] + sc[1] + sc[2] + sc[3];
    }
}

// ---------------------------------------------------------------------------
// Kernel C: reduce per-block partials, divide, write scalar output.
// ---------------------------------------------------------------------------
__global__ __launch_bounds__(256)
void final_kernel(const double* __restrict__ partS,
                  const int*    __restrict__ partC,
                  float* __restrict__ out, int n)
{
    __shared__ double sv[4];
    __shared__ long long sc[4];
    const int t = threadIdx.x;
    double a = 0.0; long long c = 0;
    for (int i = t; i < n; i += 256) { a += partS[i]; c += partC[i]; }
    for (int o = 32; o > 0; o >>= 1) {
        a += __shfl_down(a, o, 64);
        c += __shfl_down(c, o, 64);
    }
    int w = t >> 6, lane = t & 63;
    if (lane == 0) { sv[w] = a; sc[w] = c; }
    __syncthreads();
    if (t == 0) {
        double s = sv[0] + sv[1] + sv[2] + sv[3];
        long long np = sc[0] + sc[1] + sc[2] + sc[3];
        out[0] = (np == 0) ? 0.0f : (float)(s / (double)np);
    }
}

// ---------------------------------------------------------------------------
extern "C" void kernel_launch(void* const* d_in, const int* in_sizes, int n_in,
                              void* d_out, int out_size, void* d_ws, size_t ws_size,
                              hipStream_t stream)
{
    const float* locp = (const float*)d_in[0];   // [B,P,4]
    const float* conf = (const float*)d_in[1];   // [B,P,C]
    const float* dbox = (const float*)d_in[2];   // [P,4]
    const float* gt   = (const float*)d_in[3];   // [B,M,4]
    const int*   gtl  = (const int*)d_in[4];     // [B,M]

    const int P  = in_sizes[2] / 4;
    const long long BP = (long long)in_sizes[0] / 4;
    const int B  = (int)(BP / P);
    const int M  = in_sizes[4] / B;

    const int nblk = (P + 255) / 256;
    const int nPart = nblk * B;

    // ws layout: bp[B*M] u32 | garea[B*M] f32 | partS[nPart] f64 | partC i32
    char* ws = (char*)d_ws;
    unsigned* bp = (unsigned*)ws;
    size_t off = ((size_t)B * M * 4 + 15) & ~(size_t)15;
    float* garea = (float*)(ws + off);
    off += ((size_t)B * M * 4 + 15) & ~(size_t)15;
    double* partS = (double*)(ws + off);
    off += (size_t)nPart * 8;
    int* partC = (int*)(ws + off);

    dim3 gridBP((M + GGRP - 1) / GGRP, B);
    dim3 grid(nblk, B);
    bp_kernel<<<gridBP, 256, 0, stream>>>((const float4*)dbox, (const float4*)gt,
                                          bp, garea, P, M);
    loss_kernel<<<grid, 256, 0, stream>>>((const float4*)locp, conf,
                                          (const float4*)dbox, (const float4*)gt,
                                          garea, gtl, bp, partS, partC, P, M);
    final_kernel<<<1, 256, 0, stream>>>(partS, partC, (float*)d_out, nPart);
}